// Round 6
// baseline (404.964 us; speedup 1.0000x reference)
//
#include <hip/hip_runtime.h>
#include <math.h>

#define NN 25000
#define EE 300000
#define NT 1563          // ceil(25000/16)   (tail tiles)
#define NT64 391         // ceil(25000/64)   (ngemm tiles)
#define ET64 4688        // ceil(300000/64)  (egemm tiles)

typedef __attribute__((ext_vector_type(8))) short bf16x8;
typedef __attribute__((ext_vector_type(4))) float f32x4;
typedef __attribute__((ext_vector_type(2))) float f32x2;

__device__ __forceinline__ unsigned short f2bf(float f) {
    union { float f; unsigned u; } a; a.f = f;
    unsigned r = (a.u + 0x7fffu + ((a.u >> 16) & 1u)) >> 16;   // RNE
    return (unsigned short)r;
}
__device__ __forceinline__ unsigned pack2(float lo, float hi) {
    return (unsigned)f2bf(lo) | ((unsigned)f2bf(hi) << 16);
}
__device__ __forceinline__ float bflo(unsigned p) {
    union { unsigned u; float f; } a; a.u = p << 16; return a.f;
}
__device__ __forceinline__ float bfhi(unsigned p) {
    union { unsigned u; float f; } a; a.u = p & 0xffff0000u; return a.f;
}
// pack 4 floats -> 4 fp8(e4m3 OCP) in one uint
__device__ __forceinline__ unsigned packfp8x4(float a, float b, float c, float d) {
    int v = __builtin_amdgcn_cvt_pk_fp8_f32(a, b, 0, 0);
    v = __builtin_amdgcn_cvt_pk_fp8_f32(c, d, v, 1);
    return (unsigned)v;
}

// ---------------------------------------------------------------------------
// head: fused egemm + ngemm (one dispatch; block role from blockIdx.x).
//  egemm (blocks [0,ET64)): gw8[g][1+e] = fp8( ew[e] @ W1g[64:128,:] ); row 0 = 0
//  ngemm: per source X in {eu,ei,et}:
//    preB = bf16(X@Wa + ba), bf16(X@Wb + bb)
//    JG[y][1+n] = [ fp8(X@W2) 64B | bf16(X) 128B ] (192 B rows); row 0 = 0
// ---------------------------------------------------------------------------
__global__ __launch_bounds__(256) void head_kernel(
    const float* __restrict__ ew,
    const float* __restrict__ eu, const float* __restrict__ ei, const float* __restrict__ et,
    const float* __restrict__ W1u, const float* __restrict__ W1i, const float* __restrict__ W1t,
    const float* __restrict__ W2u, const float* __restrict__ W2i, const float* __restrict__ W2t,
    const float* __restrict__ bu, const float* __restrict__ bi, const float* __restrict__ bt,
    unsigned char* __restrict__ gw8, unsigned* __restrict__ preB,
    unsigned char* __restrict__ JG)
{
    __shared__ __align__(16) unsigned short stA[64 * 72];
    __shared__ __align__(16) float cS[64 * 68];
    const int t = threadIdx.x;
    const int lane = t & 63, wv = t >> 6;
    const int l15 = lane & 15, quad = lane >> 4;
    const int cw = wv * 16 + l15;                 // this wave's output col
    const int bx = blockIdx.x;

    if (bx < ET64) {
        // ================= egemm role =================
        if (bx == 0 && t < 48) {   // zero row 0 of the 3 gw8 tables (64 B each)
            int w = t >> 4;
            ((unsigned*)(gw8 + (size_t)w * (EE + 1) * 64))[t & 15] = 0u;
        }
        const float* Ws[3] = { W1u + 4096, W1i + 4096, W1t + 4096 };
        bf16x8 bf[3][2];
        #pragma unroll
        for (int w = 0; w < 3; ++w)
            #pragma unroll
            for (int ks = 0; ks < 2; ++ks)
                #pragma unroll
                for (int j = 0; j < 8; ++j)
                    bf[w][ks][j] = (short)f2bf(Ws[w][(ks * 32 + quad * 8 + j) * 64 + cw]);

        const int rowBase = bx * 64;
        #pragma unroll
        for (int i = 0; i < 4; ++i) {
            int idx = t + i * 256;
            int row = idx >> 4, cg = idx & 15;
            int gr = rowBase + row;
            float4 v4 = (gr < EE) ? *(const float4*)(ew + (size_t)gr * 64 + cg * 4)
                                  : make_float4(0.f, 0.f, 0.f, 0.f);
            uint2 pk = { pack2(v4.x, v4.y), pack2(v4.z, v4.w) };
            *(uint2*)&stA[row * 72 + cg * 4] = pk;
        }
        __syncthreads();
        bf16x8 af[4][2];
        #pragma unroll
        for (int m = 0; m < 4; ++m)
            #pragma unroll
            for (int ks = 0; ks < 2; ++ks)
                af[m][ks] = *(const bf16x8*)&stA[(m * 16 + l15) * 72 + ks * 32 + quad * 8];

        #pragma unroll
        for (int w = 0; w < 3; ++w) {
            if (w) __syncthreads();
            f32x4 acc[4];
            #pragma unroll
            for (int m = 0; m < 4; ++m) {
                acc[m].x = 0; acc[m].y = 0; acc[m].z = 0; acc[m].w = 0;
                #pragma unroll
                for (int ks = 0; ks < 2; ++ks)
                    acc[m] = __builtin_amdgcn_mfma_f32_16x16x32_bf16(af[m][ks], bf[w][ks], acc[m], 0, 0, 0);
                #pragma unroll
                for (int r = 0; r < 4; ++r)
                    cS[(m * 16 + quad * 4 + r) * 68 + cw] = acc[m][r];
            }
            __syncthreads();
            unsigned char* outg = gw8 + (size_t)w * (EE + 1) * 64 + 64;  // +1 row shift
            #pragma unroll
            for (int i = 0; i < 2; ++i) {
                int task = t + i * 256;               // 0..511
                int row = task >> 3, seg = task & 7;  // seg: 8 feats
                int gr = rowBase + row;
                if (gr < EE) {
                    float4 a = *(const float4*)&cS[row * 68 + seg * 8];
                    float4 b = *(const float4*)&cS[row * 68 + seg * 8 + 4];
                    uint2 pk = { packfp8x4(a.x, a.y, a.z, a.w),
                                 packfp8x4(b.x, b.y, b.z, b.w) };
                    *(uint2*)(outg + (size_t)gr * 64 + seg * 8) = pk;
                }
            }
        }
    } else {
        // ================= ngemm role =================
        const int yy = bx - ET64;
        const int y = yy / NT64;
        const int rowBase = (yy - y * NT64) * 64;
        if (rowBase == 0 && t < 48)   // zero row 0 of JG table y (192 B)
            ((unsigned*)(JG + (size_t)y * (NN + 1) * 192))[t] = 0u;
        const float* X; const float* Wa; const float* Wb; const float* W2;
        const float* ba; const float* bb; int oa, ob;
        switch (y) {
            case 0:  X = eu; Wa = W1i; ba = bi; oa = 0; Wb = W1t; bb = bt; ob = 1; W2 = W2u; break;
            case 1:  X = ei; Wa = W1u; ba = bu; oa = 2; Wb = W1t; bb = bt; ob = 3; W2 = W2i; break;
            default: X = et; Wa = W1u; ba = bu; oa = 4; Wb = W1i; bb = bi; ob = 5; W2 = W2t; break;
        }
        const float* Ws[3] = { Wa, Wb, W2 };
        const float bias_cw[3] = { ba[cw], bb[cw], 0.f };
        bf16x8 bf[3][2];
        #pragma unroll
        for (int w = 0; w < 3; ++w)
            #pragma unroll
            for (int ks = 0; ks < 2; ++ks)
                #pragma unroll
                for (int j = 0; j < 8; ++j)
                    bf[w][ks][j] = (short)f2bf(Ws[w][(ks * 32 + quad * 8 + j) * 64 + cw]);

        #pragma unroll
        for (int i = 0; i < 4; ++i) {
            int idx = t + i * 256;
            int row = idx >> 4, cg = idx & 15;
            int gr = rowBase + row;
            float4 v4 = (gr < NN) ? *(const float4*)(X + (size_t)gr * 64 + cg * 4)
                                  : make_float4(0.f, 0.f, 0.f, 0.f);
            uint2 pk = { pack2(v4.x, v4.y), pack2(v4.z, v4.w) };
            *(uint2*)&stA[row * 72 + cg * 4] = pk;
        }
        __syncthreads();
        bf16x8 af[4][2];
        #pragma unroll
        for (int m = 0; m < 4; ++m)
            #pragma unroll
            for (int ks = 0; ks < 2; ++ks)
                af[m][ks] = *(const bf16x8*)&stA[(m * 16 + l15) * 72 + ks * 32 + quad * 8];

        #pragma unroll
        for (int w = 0; w < 3; ++w) {
            if (w) __syncthreads();
            f32x4 acc[4];
            #pragma unroll
            for (int m = 0; m < 4; ++m) {
                acc[m].x = 0; acc[m].y = 0; acc[m].z = 0; acc[m].w = 0;
                #pragma unroll
                for (int ks = 0; ks < 2; ++ks)
                    acc[m] = __builtin_amdgcn_mfma_f32_16x16x32_bf16(af[m][ks], bf[w][ks], acc[m], 0, 0, 0);
                #pragma unroll
                for (int r = 0; r < 4; ++r)
                    cS[(m * 16 + quad * 4 + r) * 68 + cw] = acc[m][r] + bias_cw[w];
            }
            __syncthreads();
            #pragma unroll
            for (int i = 0; i < 2; ++i) {
                int task = t + i * 256;
                int row = task >> 3, seg = task & 7;
                int gr = rowBase + row;
                if (gr >= NN) continue;
                float4 a = *(const float4*)&cS[row * 68 + seg * 8];
                float4 b = *(const float4*)&cS[row * 68 + seg * 8 + 4];
                if (w < 2) {
                    int oi = (w == 0) ? oa : ob;
                    uint4 pk = { pack2(a.x, a.y), pack2(a.z, a.w),
                                 pack2(b.x, b.y), pack2(b.z, b.w) };
                    *(uint4*)(preB + ((size_t)oi * NN + gr) * 32 + seg * 4) = pk;
                } else {
                    unsigned char* dst = JG + ((size_t)y * (NN + 1) + gr + 1) * 192;
                    uint2 gj = { packfp8x4(a.x, a.y, a.z, a.w),
                                 packfp8x4(b.x, b.y, b.z, b.w) };
                    *(uint2*)(dst + seg * 8) = gj;
                    uint4 ej = *(const uint4*)&stA[row * 72 + seg * 8];
                    *(uint4*)(dst + 64 + seg * 16) = ej;
                }
            }
        }
    }
}

// ---------------------------------------------------------------------------
// atten1 v3: 2 nodes per wave. h=lane>>5 selects node, l=lane&31:
//   r = l&7 owns features 8r..8r+7, q = l>>3 owns k = 4q..4q+3.
// Pre-shifted tables (index 0 = physical zero row) -> no branches.
// f32x2 math throughout to get packed v_pk_* VALU ops.
// ---------------------------------------------------------------------------
__global__ __launch_bounds__(256) void atten1_kernel(
    const unsigned* __restrict__ preB, const unsigned char* __restrict__ gw8,
    const unsigned char* __restrict__ JG,
    const float* __restrict__ vu, const float* __restrict__ vi, const float* __restrict__ vt,
    const int* __restrict__ u_iw_j, const int* __restrict__ u_iw_w,
    const int* __restrict__ u_tw_j, const int* __restrict__ u_tw_w,
    const int* __restrict__ i_uw_j, const int* __restrict__ i_uw_w,
    const int* __restrict__ i_tw_j, const int* __restrict__ i_tw_w,
    const int* __restrict__ t_uw_j, const int* __restrict__ t_uw_w,
    const int* __restrict__ t_iw_j, const int* __restrict__ t_iw_w,
    unsigned* __restrict__ aoB)
{
    const int y = blockIdx.y;
    const int* Vj; const int* Vw; const float* v; int g;
    switch (y) {
        case 0:  Vj = u_iw_j; Vw = u_iw_w; v = vi; g = 1; break;
        case 1:  Vj = u_tw_j; Vw = u_tw_w; v = vt; g = 2; break;
        case 2:  Vj = i_uw_j; Vw = i_uw_w; v = vu; g = 0; break;
        case 3:  Vj = i_tw_j; Vw = i_tw_w; v = vt; g = 2; break;
        case 4:  Vj = t_uw_j; Vw = t_uw_w; v = vu; g = 0; break;
        default: Vj = t_iw_j; Vw = t_iw_w; v = vi; g = 1; break;
    }
    const unsigned* pre = preB + (size_t)y * NN * 32;
    const unsigned char* gw = gw8 + (size_t)g * (EE + 1) * 64;
    const unsigned char* jg = JG + (size_t)g * (NN + 1) * 192;
    unsigned*            out = aoB + (size_t)y * NN * 32;

    const int lane = threadIdx.x & 63;
    const int wv = threadIdx.x >> 6;
    const int h = lane >> 5, l = lane & 31;
    const int q = l >> 3, r = l & 7;
    const int n = blockIdx.x * 8 + wv * 2 + h;

    // per-lane node-static data: features 8r..8r+7
    const uint4 prep = *(const uint4*)(pre + (size_t)n * 32 + r * 4);
    f32x2 pf2[4];
    pf2[0].x = bflo(prep.x); pf2[0].y = bfhi(prep.x);
    pf2[1].x = bflo(prep.y); pf2[1].y = bfhi(prep.y);
    pf2[2].x = bflo(prep.z); pf2[2].y = bfhi(prep.z);
    pf2[3].x = bflo(prep.w); pf2[3].y = bfhi(prep.w);
    const float4 va = *(const float4*)(v + r * 8);
    const float4 vb = *(const float4*)(v + r * 8 + 4);
    f32x2 v2[4];
    v2[0].x = va.x; v2[0].y = va.y;  v2[1].x = va.z; v2[1].y = va.w;
    v2[2].x = vb.x; v2[2].y = vb.y;  v2[3].x = vb.z; v2[3].y = vb.w;

    // this lane's 4 neighbor slots: k = 4q..4q+3
    const int4 wi = *(const int4*)(Vw + n * 16 + q * 4);
    const int4 ji = *(const int4*)(Vj + n * 16 + q * 4);
    const int wid[4] = { wi.x, wi.y, wi.z, wi.w };
    const int jid[4] = { ji.x, ji.y, ji.z, ji.w };

    // issue ALL gathers first (12 independent loads in flight)
    uint2 gwv[4], gjv[4]; uint4 ejv[4];
    #pragma unroll
    for (int i = 0; i < 4; ++i)
        gwv[i] = *(const uint2*)(gw + (size_t)wid[i] * 64 + r * 8);
    #pragma unroll
    for (int i = 0; i < 4; ++i) {
        const unsigned char* row = jg + (size_t)jid[i] * 192;
        gjv[i] = *(const uint2*)(row + r * 8);
        ejv[i] = *(const uint4*)(row + 64 + r * 16);
    }

    // logits: x[k=4q+i] = sum_f relu(pre+gw+gj)*v, reduced over 8 r-lanes
    float xk[4];
    #pragma unroll
    for (int i = 0; i < 4; ++i) {
        f32x2 acc2; acc2.x = 0.f; acc2.y = 0.f;
        #pragma unroll
        for (int w = 0; w < 2; ++w) {
            unsigned gword = (w == 0) ? gwv[i].x : gwv[i].y;
            unsigned jword = (w == 0) ? gjv[i].x : gjv[i].y;
            f32x2 glo = __builtin_amdgcn_cvt_pk_f32_fp8((int)gword, false);
            f32x2 ghi = __builtin_amdgcn_cvt_pk_f32_fp8((int)gword, true);
            f32x2 jlo = __builtin_amdgcn_cvt_pk_f32_fp8((int)jword, false);
            f32x2 jhi = __builtin_amdgcn_cvt_pk_f32_fp8((int)jword, true);
            f32x2 t0 = pf2[w * 2] + glo + jlo;
            f32x2 t1 = pf2[w * 2 + 1] + ghi + jhi;
            t0.x = fmaxf(t0.x, 0.f); t0.y = fmaxf(t0.y, 0.f);
            t1.x = fmaxf(t1.x, 0.f); t1.y = fmaxf(t1.y, 0.f);
            acc2 += t0 * v2[w * 2];
            acc2 += t1 * v2[w * 2 + 1];
        }
        float x = acc2.x + acc2.y;
        x += __shfl_xor(x, 1, 64);
        x += __shfl_xor(x, 2, 64);
        x += __shfl_xor(x, 4, 64);
        xk[i] = x;
    }
    // softmax over 16 k (4 local regs x 4 q-groups; stays inside 32-lane half)
    float m = fmaxf(fmaxf(xk[0], xk[1]), fmaxf(xk[2], xk[3]));
    m = fmaxf(m, __shfl_xor(m, 8, 64));
    m = fmaxf(m, __shfl_xor(m, 16, 64));
    float e0 = __expf(xk[0] - m), e1 = __expf(xk[1] - m);
    float e2 = __expf(xk[2] - m), e3 = __expf(xk[3] - m);
    float s = (e0 + e1) + (e2 + e3);
    s += __shfl_xor(s, 8, 64);
    s += __shfl_xor(s, 16, 64);
    const float inv = 1.f / s;
    const float wgt[4] = { e0 * inv, e1 * inv, e2 * inv, e3 * inv };

    // weighted ej sum: weights for this lane's k's are LOCAL
    f32x2 ac[4];
    #pragma unroll
    for (int j = 0; j < 4; ++j) { ac[j].x = 0.f; ac[j].y = 0.f; }
    #pragma unroll
    for (int i = 0; i < 4; ++i) {
        const float wg = wgt[i];
        f32x2 e01; e01.x = bflo(ejv[i].x); e01.y = bfhi(ejv[i].x);
        f32x2 e23; e23.x = bflo(ejv[i].y); e23.y = bfhi(ejv[i].y);
        f32x2 e45; e45.x = bflo(ejv[i].z); e45.y = bfhi(ejv[i].z);
        f32x2 e67; e67.x = bflo(ejv[i].w); e67.y = bfhi(ejv[i].w);
        ac[0] += e01 * wg; ac[1] += e23 * wg;
        ac[2] += e45 * wg; ac[3] += e67 * wg;
    }
    float a[8] = { ac[0].x, ac[0].y, ac[1].x, ac[1].y,
                   ac[2].x, ac[2].y, ac[3].x, ac[3].y };
    #pragma unroll
    for (int j = 0; j < 8; ++j) {
        a[j] += __shfl_xor(a[j], 8, 64);
        a[j] += __shfl_xor(a[j], 16, 64);
    }
    if (q == 0) {
        uint4 pk = { pack2(a[0], a[1]), pack2(a[2], a[3]),
                     pack2(a[4], a[5]), pack2(a[6], a[7]) };
        *(uint4*)(out + (size_t)n * 32 + r * 4) = pk;
    }
}

// ---------------------------------------------------------------------------
// tail: atten2 + convs + final linear, all MFMA (16x16x32 bf16).
// 5 barriers/tile: loop-top sync removed (stage only touches uitA; its last
// reader A2 is >=2 barriers upstream), prestep folded into A2.
// ---------------------------------------------------------------------------
__global__ __launch_bounds__(256, 3) void tail_kernel(
    const float* __restrict__ eu, const float* __restrict__ ei, const float* __restrict__ et,
    const unsigned* __restrict__ aoB,
    const float* __restrict__ U, const float* __restrict__ q, const float* __restrict__ p,
    const float* __restrict__ Wbit, const float* __restrict__ Wv1,
    const float* __restrict__ Wv2, const float* __restrict__ Wv3,
    const float* __restrict__ Wf, const float* __restrict__ bfv,
    float* __restrict__ out)
{
    __shared__ __align__(16) unsigned short uitA[48 * 72];
    __shared__ __align__(16) unsigned short eNA[48 * 72];
    __shared__ __align__(16) unsigned short wcf[6 * 64 * 8];
    __shared__ __align__(16) unsigned short c_sh[16 * 584];
    __shared__ float G_sh[48 * 52];
    __shared__ float xpart[4 * 48];

    const int t = threadIdx.x;
    const int lane = t & 63;
    const int wv = t >> 6;
    const int l15 = lane & 15;
    const int quad = lane >> 4;
    const int type = blockIdx.y;
    const float* xf = (type == 0) ? eu : (type == 1) ? ei : et;
    const int cw = wv * 16 + l15;
    const float qv = q[cw], pv = p[cw], bfb = bfv[cw];

    float wb[8][3];
    #pragma unroll
    for (int c = 0; c < 8; ++c)
        #pragma unroll
        for (int s = 0; s < 3; ++s) wb[c][s] = Wbit[c * 3 + s];

    bf16x8 ufrag[2];
    #pragma unroll
    for (int ks = 0; ks < 2; ++ks)
        #pragma unroll
        for (int j = 0; j < 8; ++j) {
            int f = ks * 32 + quad * 8 + j;
            ufrag[ks][j] = (short)f2bf(U[f * 64 + cw]);
        }
    bf16x8 wff[18];
    #pragma unroll
    for (int ks = 0; ks < 18; ++ks)
        #pragma unroll
        for (int j = 0; j < 8; ++j) {
            int k = ks * 32 + quad * 8 + j;
            float w = (k < 560) ? Wf[(size_t)k * 64 + cw] : 0.f;
            wff[ks][j] = (short)f2bf(w);
        }
    for (int slot = t; slot < 384; slot += 256) {
        int fi = slot >> 6, l = slot & 63;
        int nt_ = fi >> 1, ks = fi & 1;
        int r = nt_ * 16 + (l & 15);
        unsigned short vals[8];
        #pragma unroll
        for (int j = 0; j < 8; ++j) {
            int f = ks * 32 + (l >> 4) * 8 + j;
            float wv_;
            if (r < 8)       wv_ = Wv1[r * 64 + f];
            else if (r < 24) { int u = r - 8;  wv_ = Wv2[(u >> 1) * 128 + (u & 1) * 64 + f]; }
            else             { int u = r - 24; wv_ = Wv3[(u / 3) * 192 + (u % 3) * 64 + f]; }
            vals[j] = f2bf(wv_);
        }
        uint4 pk = { (unsigned)vals[0] | ((unsigned)vals[1] << 16),
                     (unsigned)vals[2] | ((unsigned)vals[3] << 16),
                     (unsigned)vals[4] | ((unsigned)vals[5] << 16),
                     (unsigned)vals[6] | ((unsigned)vals[7] << 16) };
        *(uint4*)&wcf[slot * 8] = pk;
    }

    for (int tile = blockIdx.x; tile < NT; tile += gridDim.x) {
        const int nodeBase = tile * 16;
        // ---- stage uit (48 rows = 16 nodes x 3 sources) as bf16 ----
        #pragma unroll
        for (int i = 0; i < 3; ++i) {
            int idx = t + i * 256;
            int row = idx >> 4, cg = idx & 15;
            int nl = row / 3, s = row - nl * 3;
            int n = nodeBase + nl;
            uint2 pk;
            if (s == type) {
                float4 v4 = (n < NN) ? *(const float4*)(xf + (size_t)n * 64 + cg * 4)
                                     : make_float4(0.f, 0.f, 0.f, 0.f);
                pk.x = pack2(v4.x, v4.y); pk.y = pack2(v4.z, v4.w);
            } else {
                int aoidx = (type == 0) ? (s - 1)
                          : (type == 1) ? ((s == 0) ? 2 : 3)
                                        : ((s == 0) ? 4 : 5);
                pk = (n < NN) ? *(const uint2*)(aoB + ((size_t)aoidx * NN + n) * 32 + cg * 2)
                              : make_uint2(0u, 0u);
            }
            *(uint2*)&uitA[row * 72 + cg * 4] = pk;
        }
        __syncthreads();                                   // barrier 1
        // ---- phase A: av = uit @ U; per-wave column-strip partial x ----
        {
            f32x4 av[3];
            #pragma unroll
            for (int mt = 0; mt < 3; ++mt) { av[mt].x = 0; av[mt].y = 0; av[mt].z = 0; av[mt].w = 0; }
            #pragma unroll
            for (int mt = 0; mt < 3; ++mt)
                #pragma unroll
                for (int ks = 0; ks < 2; ++ks) {
                    bf16x8 a = *(const bf16x8*)&uitA[(mt * 16 + l15) * 72 + ks * 32 + quad * 8];
                    av[mt] = __builtin_amdgcn_mfma_f32_16x16x32_bf16(a, ufrag[ks], av[mt], 0, 0, 0);
                }
            #pragma unroll
            for (int mt = 0; mt < 3; ++mt)
                #pragma unroll
                for (int r = 0; r < 4; ++r) {
                    float val = fmaxf(av[mt][r] + qv, 0.f) * pv;
                    val += __shfl_xor(val, 1, 64); val += __shfl_xor(val, 2, 64);
                    val += __shfl_xor(val, 4, 64); val += __shfl_xor(val, 8, 64);
                    if (l15 == 0) xpart[wv * 48 + mt * 16 + quad * 4 + r] = val;
                }
        }
        __syncthreads();                                   // barrier 2
        // ---- phase A2: per-node softmax (from xpart) + en + bit conv ----
        #pragma unroll
        for (int i = 0; i < 2; ++i) {
            int task = t + i * 256;
            int nl = task >> 5, fp = task & 31;
            float xv0 = xpart[nl * 3 + 0] + xpart[48 + nl * 3 + 0]
                      + xpart[96 + nl * 3 + 0] + xpart[144 + nl * 3 + 0];
            float xv1 = xpart[nl * 3 + 1] + xpart[48 + nl * 3 + 1]
                      + xpart[96 + nl * 3 + 1] + xpart[144 + nl * 3 + 1];
            float xv2 = xpart[nl * 3 + 2] + xpart[48 + nl * 3 + 2]
                      + xpart[96 + nl * 3 + 2] + xpart[144 + nl * 3 + 2];
            float mm = fmaxf(xv0, fmaxf(xv1, xv2));
            float ex0 = __expf(xv0 - mm), ex1 = __expf(xv1 - mm), ex2 = __expf(xv2 - mm);
            float inv = 1.f / (ex0 + ex1 + ex2);
            float b0 = ex0 * inv, b1 = ex1 * inv, b2 = ex2 * inv;
            unsigned u0 = *(const unsigned*)&uitA[(nl * 3 + 0) * 72 + fp * 2];
            unsigned u1 = *(const unsigned*)&uitA[(nl * 3 + 1) * 72 + fp * 2];
            unsigned u2 = *(const unsigned*)&uitA[(nl * 3 + 2) * 72 + fp * 2];
            float e0l = b0 * bflo(u0), e0h = b0 * bfhi(u0);
            float e1l = b1 * bflo(u1), e1h = b1 * bfhi(u1);
            float e2l = b2 * bflo(u2), e2h = b2 * bfhi(u2);
            *(unsigned*)&eNA[(nl * 3 + 0) * 72 + fp * 2] = pack2(e0l, e0h);
            *(unsigned*)&eNA[(nl * 3 + 1) * 72 + fp * 2] = pack2(e1l, e1h);
            *(unsigned*)&eNA[(nl * 3 + 2) * 72 + fp * 2] = pack2(e2l, e2h);
            #pragma unroll
            for (int c = 0; c < 8; ++c) {
                float lo = fmaxf(wb[c][0] * e0l + wb[c][1] * e1l + wb[c][2] * e2l, 0.f);
                float hi = fmaxf(wb[c][0] * e0h + wb[c][1] * e1h + wb[c][2] * e2h, 0.f);
                *(unsigned*)&c_sh[nl * 584 + c * 64 + fp * 2] = pack2(lo, hi);
            }
        }
        __syncthreads();                                   // barrier 3
        // ---- phase B: G = eN @ WconvT; 9 (m,n) 16x16 tiles round-robin ----
        #pragma unroll
        for (int pi = 0; pi < 3; ++pi) {
            int pr = wv + pi * 4;
            if (pr < 9) {
                int mm = pr / 3, nn_ = pr - mm * 3;
                f32x4 g; g.x = 0; g.y = 0; g.z = 0; g.w = 0;
                #pragma unroll
                for (int ks = 0; ks < 2; ++ks) {
                    bf16x8 a = *(const bf16x8*)&eNA[(mm * 16 + l15) * 72 + ks * 32 + quad * 8];
                    bf16x8 b = *(const bf16x8*)&wcf[((nn_ * 2 + ks) * 64 + lane) * 8];
                    g = __builtin_amdgcn_mfma_f32_16x16x32_bf16(a, b, g, 0, 0, 0);
                }
                #pragma unroll
                for (int r = 0; r < 4; ++r)
                    G_sh[(mm * 16 + quad * 4 + r) * 52 + nn_ * 16 + l15] = g[r];
            }
        }
        __syncthreads();                                   // barrier 4
        // ---- phase B2: vec conv assembly -> c_sh[512:576] ----
        #pragma unroll
        for (int i = 0; i < 4; ++i) {
            int task = t + i * 256;
            int vvv = task >> 4, nl = task & 15;
            unsigned short res = 0;
            if (vvv < 24) {
                int c = vvv / 3, s = vvv - c * 3;
                res = f2bf(fmaxf(G_sh[(nl * 3 + s) * 52 + c], 0.f));
            } else if (vvv < 40) {
                int u = vvv - 24, c = u >> 1, s = u & 1;
                float val = G_sh[(nl * 3 + s) * 52 + 8 + 2 * c]
                          + G_sh[(nl * 3 + s + 1) * 52 + 8 + 2 * c + 1];
                res = f2bf(fmaxf(val, 0.f));
            } else if (vvv < 48) {
                int c = vvv - 40;
                float val = G_sh[(nl * 3 + 0) * 52 + 24 + 3 * c]
                          + G_sh[(nl * 3 + 1) * 52 + 24 + 3 * c + 1]
                          + G_sh[(nl * 3 + 2) * 52 + 24 + 3 * c + 2];
                res = f2bf(fmaxf(val, 0.f));
            }
            c_sh[nl * 584 + 512 + vvv] = res;
        }
        __syncthreads();                                   // barrier 5
        // ---- phase C: out = relu(c[16,576] @ Wf + bf) ----
        {
            f32x4 acc; acc.x = 0; acc.y = 0; acc.z = 0; acc.w = 0;
            const unsigned short* ap = &c_sh[l15 * 584 + quad * 8];
            #pragma unroll
            for (int ks = 0; ks < 18; ++ks) {
                bf16x8 a = *(const bf16x8*)(ap + ks * 32);
                acc = __builtin_amdgcn_mfma_f32_16x16x32_bf16(a, wff[ks], acc, 0, 0, 0);
            }
            float* outT = out + (size_t)type * NN * 64;
            #pragma unroll
            for (int r = 0; r < 4; ++r) {
                int node = nodeBase + quad * 4 + r;
                if (node < NN) outT[(size_t)node * 64 + cw] = fmaxf(acc[r] + bfb, 0.f);
            }
        }
    }
}

// ---------------------------------------------------------------------------
extern "C" void kernel_launch(void* const* d_in, const int* in_sizes, int n_in,
                              void* d_out, int out_size, void* d_ws, size_t ws_size,
                              hipStream_t stream)
{
    const float* eu = (const float*)d_in[0];
    const float* ei = (const float*)d_in[1];
    const float* et = (const float*)d_in[2];
    const float* ew = (const float*)d_in[3];
    const int* u_iw_j = (const int*)d_in[4];
    const int* u_iw_w = (const int*)d_in[5];
    const int* u_tw_j = (const int*)d_in[6];
    const int* u_tw_w = (const int*)d_in[7];
    const int* i_uw_j = (const int*)d_in[8];
    const int* i_uw_w = (const int*)d_in[9];
    const int* i_tw_j = (const int*)d_in[10];
    const int* i_tw_w = (const int*)d_in[11];
    const int* t_uw_j = (const int*)d_in[12];
    const int* t_uw_w = (const int*)d_in[13];
    const int* t_iw_j = (const int*)d_in[14];
    const int* t_iw_w = (const int*)d_in[15];
    const float* W1_user = (const float*)d_in[16];
    const float* W2_user = (const float*)d_in[17];
    const float* b_user  = (const float*)d_in[18];
    const float* v_user  = (const float*)d_in[19];
    const float* W1_item = (const float*)d_in[20];
    const float* W2_item = (const float*)d_in[21];
    const float* b_item  = (const float*)d_in[22];
    const float* v_item  = (const float*)d_in[23];
    const float* W1_tag  = (const float*)d_in[24];
    const float* W2_tag  = (const float*)d_in[25];
    const float* b_tag   = (const float*)d_in[26];
    const float* v_tag   = (const float*)d_in[27];
    const float* U    = (const float*)d_in[28];
    const float* q    = (const float*)d_in[29];
    const float* p    = (const float*)d_in[30];
    const float* Wbit = (const float*)d_in[31];
    const float* Wv1  = (const float*)d_in[32];
    const float* Wv2  = (const float*)d_in[33];
    const float* Wv3  = (const float*)d_in[34];
    const float* Wf   = (const float*)d_in[35];
    const float* bfv  = (const float*)d_in[36];
    float* out = (float*)d_out;

    // ---- workspace (~110 MB):
    // gw8: 3*(E+1)*64 B | preB: 6*N*128 B | JG: 3*(N+1)*192 B | aoB: 6*N*128 B
    unsigned char* gw8 = (unsigned char*)d_ws;
    unsigned* preB = (unsigned*)(gw8 + (size_t)3 * (EE + 1) * 64);
    unsigned char* JG = (unsigned char*)(preB + (size_t)6 * NN * 32);
    unsigned* aoB = (unsigned*)(JG + (size_t)3 * (NN + 1) * 192);

    const dim3 blk(256);

    head_kernel<<<ET64 + 3 * NT64, blk, 0, stream>>>(
        ew, eu, ei, et,
        W1_user, W1_item, W1_tag, W2_user, W2_item, W2_tag,
        b_user, b_item, b_tag, gw8, preB, JG);

    atten1_kernel<<<dim3(NN / 8, 6), blk, 0, stream>>>(
        preB, gw8, JG, v_user, v_item, v_tag,
        u_iw_j, u_iw_w, u_tw_j, u_tw_w, i_uw_j, i_uw_w,
        i_tw_j, i_tw_w, t_uw_j, t_uw_w, t_iw_j, t_iw_w, aoB);

    tail_kernel<<<dim3(256, 3), blk, 0, stream>>>(
        eu, ei, et, aoB,
        U, q, p, Wbit, Wv1, Wv2, Wv3, Wf, bfv, out);
}